// Round 2
// baseline (258.104 us; speedup 1.0000x reference)
//
#include <hip/hip_runtime.h>
#include <math.h>

#define BLOCK 256
#define F4PB (BLOCK * 9 / 4)   // 576 float4 tiles per block

__device__ __forceinline__ float frcp(float x)   { return __builtin_amdgcn_rcpf(x); }
__device__ __forceinline__ float frsq(float x)   { return __builtin_amdgcn_rsqf(x); }
__device__ __forceinline__ float fsqrt_r(float x){ return __builtin_amdgcn_sqrtf(x); }

// Hastings acos approximation, abs err ~6.8e-5 rad (feeds only eigenvector
// extraction; sigma is recovered variationally so this precision is ample).
__device__ __forceinline__ float acos_fast(float x) {
    float ax = fabsf(x);
    float p = fmaf(ax, -0.0187293f, 0.0742610f);
    p = fmaf(ax, p, -0.2121144f);
    p = fmaf(ax, p, 1.5707288f);
    float r = fsqrt_r(fmaxf(1.0f - ax, 0.0f)) * p;
    return (x < 0.0f) ? (3.14159265358979f - r) : r;
}

// Largest-norm cross product of the three row pairs of a symmetric 3x3
// matrix with rows (r0x,r0y,r0z),(r0y,r1y,r1z),(r0z,r1z,r2z) given explicitly.
// Returns unnormalized best cross + its squared norm.
__device__ __forceinline__ void best_cross(
    float r0x, float r0y, float r0z,
    float r1x, float r1y, float r1z,
    float r2x, float r2y, float r2z,
    float& bx, float& by, float& bz, float& bn)
{
    float c0x = fmaf(r0y,r1z, -r0z*r1y);   // row0 x row1
    float c0y = fmaf(r0z,r1x, -r0x*r1z);
    float c0z = fmaf(r0x,r1y, -r0y*r1x);
    float c1x = fmaf(r0y,r2z, -r0z*r2y);   // row0 x row2
    float c1y = fmaf(r0z,r2x, -r0x*r2z);
    float c1z = fmaf(r0x,r2y, -r0y*r2x);
    float c2x = fmaf(r1y,r2z, -r1z*r2y);   // row1 x row2
    float c2y = fmaf(r1z,r2x, -r1x*r2z);
    float c2z = fmaf(r1x,r2y, -r1y*r2x);
    float n0 = fmaf(c0x,c0x, fmaf(c0y,c0y, c0z*c0z));
    float n1 = fmaf(c1x,c1x, fmaf(c1y,c1y, c1z*c1z));
    float n2 = fmaf(c2x,c2x, fmaf(c2y,c2y, c2z*c2z));
    bool b1 = n1 > n0;
    float sx = b1 ? c1x : c0x, sy = b1 ? c1y : c0y, sz = b1 ? c1z : c0z;
    float sn = b1 ? n1 : n0;
    bool b2 = n2 > sn;
    bx = b2 ? c2x : sx; by = b2 ? c2y : sy; bz = b2 ? c2z : sz;
    bn = b2 ? n2 : sn;
}

__global__ __launch_bounds__(BLOCK) void dp_kernel(
    const float* __restrict__ F,
    const float* __restrict__ p_yml,
    const float* __restrict__ p_nu,
    const float* __restrict__ p_fa,
    const float* __restrict__ p_coh,
    float* __restrict__ out,
    int n_elem)
{
    __shared__ float lds[BLOCK * 9];
    const int t_id    = threadIdx.x;
    const int nfloats = n_elem * 9;                       // <= 36e6, fits int
    const int base_f  = (int)blockIdx.x * (BLOCK * 9);    // 32-bit addressing

    // ---- stage in: coalesced float4 ----
    #pragma unroll
    for (int j = 0; j < 3; ++j) {
        int idx = t_id + j * BLOCK;
        if (idx < F4PB) {
            int g4 = (base_f >> 2) + idx;
            int gf = g4 << 2;
            if (gf + 4 <= nfloats) {
                ((float4*)lds)[idx] = ((const float4*)F)[g4];
            } else {
                #pragma unroll
                for (int k = 0; k < 4; ++k)
                    if (gf + k < nfloats) lds[idx * 4 + k] = F[gf + k];
            }
        }
    }
    __syncthreads();

    // original A: aRC = row R, col C
    float a00, a01, a02, a10, a11, a12, a20, a21, a22;
    {
        const float* p = lds + t_id * 9;   // stride 9: 2-way bank alias only (free)
        a00 = p[0]; a01 = p[1]; a02 = p[2];
        a10 = p[3]; a11 = p[4]; a12 = p[5];
        a20 = p[6]; a21 = p[7]; a22 = p[8];
    }
    // barrier for LDS reuse is just before output staging.

    // ---- material params (uniform) ----
    const float yml = p_yml[0];
    const float nu  = p_nu[0];
    const float fa  = p_fa[0];
    const float coh = p_coh[0];
    const float E     = __expf(yml);
    const float sphi  = __sinf(fa * 0.017453292519943295f);
    const float alpha = 1.632993161855452f * sphi * frcp(3.0f - sphi);
    const float mu    = E * 0.5f * frcp(1.0f + nu);
    const float la    = E * nu * frcp((1.0f + nu) * (1.0f - 2.0f * nu));
    const float ratio = (3.0f * la + 2.0f * mu) * frcp(2.0f * mu) * alpha;

    // ---- Gram matrix S = A^T A (symmetric, entries over A's columns) ----
    float s00 = fmaf(a00,a00, fmaf(a10,a10, a20*a20));
    float s11 = fmaf(a01,a01, fmaf(a11,a11, a21*a21));
    float s22 = fmaf(a02,a02, fmaf(a12,a12, a22*a22));
    float s01 = fmaf(a00,a01, fmaf(a10,a11, a20*a21));
    float s02 = fmaf(a00,a02, fmaf(a10,a12, a20*a22));
    float s12 = fmaf(a01,a02, fmaf(a11,a12, a21*a22));

    // ---- closed-form eigenvalues (trigonometric cubic, Eberly/Smith) ----
    float q   = (s00 + s11 + s22) * (1.0f/3.0f);
    float b00 = s00 - q, b11 = s11 - q, b22 = s22 - q;
    float offsq = fmaf(s01,s01, fmaf(s02,s02, s12*s12));
    float p2  = fmaf(b00,b00, fmaf(b11,b11, fmaf(b22,b22, 2.0f*offsq)));
    float pp  = fsqrt_r(p2 * (1.0f/6.0f));
    float pinv = frcp(fmaxf(pp, 1e-10f));       // clamp: pinv^3 <= 1e30, no Inf
    float det = b00*fmaf(b11,b22, -s12*s12)
              - s01*fmaf(s01,b22, -s12*s02)
              + s02*fmaf(s01,s12, -b11*s02);
    float rdet = 0.5f * det * pinv * pinv * pinv;
    rdet = fminf(fmaxf(rdet, -1.0f), 1.0f);
    float phi  = acos_fast(rdet) * (1.0f/3.0f);          // in [0, pi/3]
    float lam0 = fmaf(2.0f*pp, __cosf(phi), q);                    // largest
    float lam2 = fmaf(2.0f*pp, __cosf(phi + 2.0943951023931953f), q); // smallest

    // ---- v0: null direction of (S - lam0 I) via best row cross ----
    float bx, by, bz, bn;
    best_cross(s00-lam0, s01, s02,
               s01, s11-lam0, s12,
               s02, s12, s22-lam0, bx, by, bz, bn);
    bool ok0 = bn > 1e-24f;                     // exact-zero guard only
    float ir0 = frsq(fmaxf(bn, 1e-30f));
    float v00 = ok0 ? bx*ir0 : 1.0f;
    float v10 = ok0 ? by*ir0 : 0.0f;
    float v20 = ok0 ? bz*ir0 : 0.0f;

    // ---- v2: null direction of (S - lam2 I), orthogonalized against v0 ----
    best_cross(s00-lam2, s01, s02,
               s01, s11-lam2, s12,
               s02, s12, s22-lam2, bx, by, bz, bn);
    // robust fallback perp to v0: f = v0 x e_min  (|f| >= sqrt(2/3))
    float axv = fabsf(v00), ayv = fabsf(v10), azv = fabsf(v20);
    bool xm = (axv <= ayv) && (axv <= azv);
    bool ym = (!xm) && (ayv <= azv);
    float ex = xm ? 1.0f : 0.0f;
    float ey = ym ? 1.0f : 0.0f;
    float ez = (xm || ym) ? 0.0f : 1.0f;
    float fx = fmaf(v10,ez, -v20*ey);
    float fy = fmaf(v20,ex, -v00*ez);
    float fz = fmaf(v00,ey, -v10*ex);
    bool ok2 = bn > 1e-24f;
    float wx = ok2 ? bx : fx, wy = ok2 ? by : fy, wz = ok2 ? bz : fz;
    // Gram-Schmidt against v0 (exact orthogonality for clustered eigvals)
    float dp = fmaf(wx,v00, fmaf(wy,v10, wz*v20));
    wx = fmaf(-dp, v00, wx); wy = fmaf(-dp, v10, wy); wz = fmaf(-dp, v20, wz);
    float wn = fmaf(wx,wx, fmaf(wy,wy, wz*wz));
    bool okw = wn > 1e-24f;
    wx = okw ? wx : fx; wy = okw ? wy : fy; wz = okw ? wz : fz;
    wn = okw ? wn : fmaf(fx,fx, fmaf(fy,fy, fz*fz));
    float irw = frsq(fmaxf(wn, 1e-30f));
    float v02 = wx*irw, v12 = wy*irw, v22 = wz*irw;
    // v1 = v2 x v0  → (v0,v1,v2) right-handed
    float v01 = fmaf(v12,v20, -v22*v10);
    float v11 = fmaf(v22,v00, -v02*v20);
    float v21 = fmaf(v02,v10, -v12*v00);

    // ---- U columns: u_i = normalize(A v_i); sigma_i^2 = |A v_i|^2 ----
    float q0 = fmaf(a00,v00, fmaf(a01,v10, a02*v20));
    float q1 = fmaf(a10,v00, fmaf(a11,v10, a12*v20));
    float q2 = fmaf(a20,v00, fmaf(a21,v10, a22*v20));
    float m0 = fmaf(q0,q0, fmaf(q1,q1, q2*q2));
    float i0 = frsq(fmaxf(m0, 1e-30f));
    float u00 = q0*i0, u10 = q1*i0, u20 = q2*i0;

    q0 = fmaf(a00,v01, fmaf(a01,v11, a02*v21));
    q1 = fmaf(a10,v01, fmaf(a11,v11, a12*v21));
    q2 = fmaf(a20,v01, fmaf(a21,v11, a22*v21));
    float m1 = fmaf(q0,q0, fmaf(q1,q1, q2*q2));
    float i1 = frsq(fmaxf(m1, 1e-30f));
    float u01 = q0*i1, u11 = q1*i1, u21 = q2*i1;

    float u02 = fmaf(u10,u21, -u20*u11);       // u2 = u0 x u1
    float u12 = fmaf(u20,u01, -u00*u21);
    float u22 = fmaf(u00,u11, -u10*u01);

    // signed third singular term: s2 = u2^T A v2
    float w0 = fmaf(a00,v02, fmaf(a01,v12, a02*v22));
    float w1 = fmaf(a10,v02, fmaf(a11,v12, a12*v22));
    float w2 = fmaf(a20,v02, fmaf(a21,v12, a22*v22));
    float s2 = fmaf(u02,w0, fmaf(u12,w1, u22*w2));

    // ---- Drucker-Prager return mapping on log strains ----
    // log(max(sigma,0.05)) = 0.5*log(max(sigma^2,0.0025)): use |Av|^2 directly
    float e0 = 0.5f * __logf(fmaxf(m0, 0.0025f));
    float e1 = 0.5f * __logf(fmaxf(m1, 0.0025f));
    float e2 = __logf(fmaxf(fabsf(s2), 0.05f));
    float tr  = e0 + e1 + e2;
    float tr3 = tr * (1.0f / 3.0f);
    float h0 = e0 - tr3, h1 = e1 - tr3, h2 = e2 - tr3;
    float hn = fsqrt_r(fmaf(h0,h0, fmaf(h1,h1, h2*h2)));
    hn = fmaxf(hn, 1e-10f);
    float st = tr - coh * 3.0f;
    float dg = hn + ratio * st;
    float sc = fmaxf(dg, 0.0f) * frcp(hn);
    bool yield = st < 0.0f;
    float ec0 = yield ? fmaf(-sc, h0, e0) : coh;
    float ec1 = yield ? fmaf(-sc, h1, e1) : coh;
    float ec2 = yield ? fmaf(-sc, h2, e2) : coh;
    float f0 = __expf(ec0);
    float f1 = __expf(ec1);
    float f2 = copysignf(__expf(ec2), s2);     // fold third-term sign into scale

    // ---- F_corrected = sum_k f_k * u_k * v_k^T ----
    float w00 = u00*f0, w01 = u01*f1, w02 = u02*f2;
    float w10 = u10*f0, w11 = u11*f1, w12 = u12*f2;
    float w20 = u20*f0, w21 = u21*f1, w22 = u22*f2;
    float r00 = fmaf(w00,v00, fmaf(w01,v01, w02*v02));
    float r01 = fmaf(w00,v10, fmaf(w01,v11, w02*v12));
    float r02 = fmaf(w00,v20, fmaf(w01,v21, w02*v22));
    float r10 = fmaf(w10,v00, fmaf(w11,v01, w12*v02));
    float r11 = fmaf(w10,v10, fmaf(w11,v11, w12*v12));
    float r12 = fmaf(w10,v20, fmaf(w11,v21, w12*v22));
    float r20 = fmaf(w20,v00, fmaf(w21,v01, w22*v02));
    float r21 = fmaf(w20,v10, fmaf(w21,v11, w22*v12));
    float r22 = fmaf(w20,v20, fmaf(w21,v21, w22*v22));

    // ---- stage out through LDS, coalesced ----
    __syncthreads();   // all input-stage LDS reads complete before reuse
    {
        float* p = lds + t_id * 9;   // tail threads write garbage to own slot: harmless
        p[0]=r00; p[1]=r01; p[2]=r02;
        p[3]=r10; p[4]=r11; p[5]=r12;
        p[6]=r20; p[7]=r21; p[8]=r22;
    }
    __syncthreads();

    #pragma unroll
    for (int j = 0; j < 3; ++j) {
        int idx = t_id + j * BLOCK;
        if (idx < F4PB) {
            int g4 = (base_f >> 2) + idx;
            int gf = g4 << 2;
            if (gf + 4 <= nfloats) {
                ((float4*)out)[g4] = ((float4*)lds)[idx];
            } else {
                #pragma unroll
                for (int k = 0; k < 4; ++k)
                    if (gf + k < nfloats) out[gf + k] = lds[idx * 4 + k];
            }
        }
    }
}

extern "C" void kernel_launch(void* const* d_in, const int* in_sizes, int n_in,
                              void* d_out, int out_size, void* d_ws, size_t ws_size,
                              hipStream_t stream) {
    const float* F = (const float*)d_in[0];
    const int n_elem = in_sizes[0] / 9;
    const int grid = (n_elem + BLOCK - 1) / BLOCK;
    dp_kernel<<<grid, BLOCK, 0, stream>>>(
        F,
        (const float*)d_in[1], (const float*)d_in[2],
        (const float*)d_in[3], (const float*)d_in[4],
        (float*)d_out, n_elem);
}

// Round 3
// 257.233 us; speedup vs baseline: 1.0034x; 1.0034x over previous
//
#include <hip/hip_runtime.h>
#include <math.h>

#define BLOCK 256
#define EPT   2                  // elements per thread (independent ILP chains)
#define EPB   (BLOCK * EPT)      // 512 elements per block
#define FPB   (EPB * 9)          // 4608 floats per block
#define F4PB  (FPB / 4)          // 1152 float4 tiles per block

__device__ __forceinline__ float frcp(float x)   { return __builtin_amdgcn_rcpf(x); }
__device__ __forceinline__ float frsq(float x)   { return __builtin_amdgcn_rsqf(x); }
__device__ __forceinline__ float fsqrt_r(float x){ return __builtin_amdgcn_sqrtf(x); }

// Hastings acos approximation, abs err ~6.8e-5 rad (feeds only eigenvector
// extraction; sigma is recovered variationally so this precision is ample).
__device__ __forceinline__ float acos_fast(float x) {
    float ax = fabsf(x);
    float p = fmaf(ax, -0.0187293f, 0.0742610f);
    p = fmaf(ax, p, -0.2121144f);
    p = fmaf(ax, p, 1.5707288f);
    float r = fsqrt_r(fmaxf(1.0f - ax, 0.0f)) * p;
    return (x < 0.0f) ? (3.14159265358979f - r) : r;
}

// Largest-norm cross product among the three row pairs of a symmetric 3x3.
__device__ __forceinline__ void best_cross(
    float r0x, float r0y, float r0z,
    float r1x, float r1y, float r1z,
    float r2x, float r2y, float r2z,
    float& bx, float& by, float& bz, float& bn)
{
    float c0x = fmaf(r0y,r1z, -r0z*r1y);   // row0 x row1
    float c0y = fmaf(r0z,r1x, -r0x*r1z);
    float c0z = fmaf(r0x,r1y, -r0y*r1x);
    float c1x = fmaf(r0y,r2z, -r0z*r2y);   // row0 x row2
    float c1y = fmaf(r0z,r2x, -r0x*r2z);
    float c1z = fmaf(r0x,r2y, -r0y*r2x);
    float c2x = fmaf(r1y,r2z, -r1z*r2y);   // row1 x row2
    float c2y = fmaf(r1z,r2x, -r1x*r2z);
    float c2z = fmaf(r1x,r2y, -r1y*r2x);
    float n0 = fmaf(c0x,c0x, fmaf(c0y,c0y, c0z*c0z));
    float n1 = fmaf(c1x,c1x, fmaf(c1y,c1y, c1z*c1z));
    float n2 = fmaf(c2x,c2x, fmaf(c2y,c2y, c2z*c2z));
    bool b1 = n1 > n0;
    float sx = b1 ? c1x : c0x, sy = b1 ? c1y : c0y, sz = b1 ? c1z : c0z;
    float sn = b1 ? n1 : n0;
    bool b2 = n2 > sn;
    bx = b2 ? c2x : sx; by = b2 ? c2y : sy; bz = b2 ? c2z : sz;
    bn = b2 ? n2 : sn;
}

// Closed-form 3x3 SVD (symmetric eigensolve of A^T A) + Drucker-Prager
// return mapping. Pure reg-to-reg, branchless: two calls interleave freely.
__device__ __forceinline__ void dp_solve(
    float a00, float a01, float a02,
    float a10, float a11, float a12,
    float a20, float a21, float a22,
    float coh, float ratio,
    float& r00, float& r01, float& r02,
    float& r10, float& r11, float& r12,
    float& r20, float& r21, float& r22)
{
    // ---- Gram matrix S = A^T A ----
    float s00 = fmaf(a00,a00, fmaf(a10,a10, a20*a20));
    float s11 = fmaf(a01,a01, fmaf(a11,a11, a21*a21));
    float s22 = fmaf(a02,a02, fmaf(a12,a12, a22*a22));
    float s01 = fmaf(a00,a01, fmaf(a10,a11, a20*a21));
    float s02 = fmaf(a00,a02, fmaf(a10,a12, a20*a22));
    float s12 = fmaf(a01,a02, fmaf(a11,a12, a21*a22));

    // ---- closed-form eigenvalues (trigonometric cubic) ----
    float q   = (s00 + s11 + s22) * (1.0f/3.0f);
    float b00 = s00 - q, b11 = s11 - q, b22 = s22 - q;
    float offsq = fmaf(s01,s01, fmaf(s02,s02, s12*s12));
    float p2  = fmaf(b00,b00, fmaf(b11,b11, fmaf(b22,b22, 2.0f*offsq)));
    float pp  = fsqrt_r(p2 * (1.0f/6.0f));
    float pinv = frcp(fmaxf(pp, 1e-10f));       // clamp: pinv^3 <= 1e30, no Inf
    float det = b00*fmaf(b11,b22, -s12*s12)
              - s01*fmaf(s01,b22, -s12*s02)
              + s02*fmaf(s01,s12, -b11*s02);
    float rdet = 0.5f * det * pinv * pinv * pinv;
    rdet = fminf(fmaxf(rdet, -1.0f), 1.0f);
    float phi  = acos_fast(rdet) * (1.0f/3.0f);          // in [0, pi/3]
    float lam0 = fmaf(2.0f*pp, __cosf(phi), q);                       // largest
    float lam2 = fmaf(2.0f*pp, __cosf(phi + 2.0943951023931953f), q); // smallest

    // ---- v0: null direction of (S - lam0 I) ----
    float bx, by, bz, bn;
    best_cross(s00-lam0, s01, s02,
               s01, s11-lam0, s12,
               s02, s12, s22-lam0, bx, by, bz, bn);
    bool ok0 = bn > 1e-24f;
    float ir0 = frsq(fmaxf(bn, 1e-30f));
    float v00 = ok0 ? bx*ir0 : 1.0f;
    float v10 = ok0 ? by*ir0 : 0.0f;
    float v20 = ok0 ? bz*ir0 : 0.0f;

    // ---- v2: null direction of (S - lam2 I), orthogonalized against v0 ----
    best_cross(s00-lam2, s01, s02,
               s01, s11-lam2, s12,
               s02, s12, s22-lam2, bx, by, bz, bn);
    float axv = fabsf(v00), ayv = fabsf(v10), azv = fabsf(v20);
    bool xm = (axv <= ayv) && (axv <= azv);
    bool ym = (!xm) && (ayv <= azv);
    float ex = xm ? 1.0f : 0.0f;
    float ey = ym ? 1.0f : 0.0f;
    float ez = (xm || ym) ? 0.0f : 1.0f;
    float fx = fmaf(v10,ez, -v20*ey);          // fallback perp to v0
    float fy = fmaf(v20,ex, -v00*ez);
    float fz = fmaf(v00,ey, -v10*ex);
    bool ok2 = bn > 1e-24f;
    float wx = ok2 ? bx : fx, wy = ok2 ? by : fy, wz = ok2 ? bz : fz;
    float dp = fmaf(wx,v00, fmaf(wy,v10, wz*v20));   // Gram-Schmidt vs v0
    wx = fmaf(-dp, v00, wx); wy = fmaf(-dp, v10, wy); wz = fmaf(-dp, v20, wz);
    float wn = fmaf(wx,wx, fmaf(wy,wy, wz*wz));
    bool okw = wn > 1e-24f;
    wx = okw ? wx : fx; wy = okw ? wy : fy; wz = okw ? wz : fz;
    wn = okw ? wn : fmaf(fx,fx, fmaf(fy,fy, fz*fz));
    float irw = frsq(fmaxf(wn, 1e-30f));
    float v02 = wx*irw, v12 = wy*irw, v22 = wz*irw;
    // v1 = v2 x v0 -> (v0,v1,v2) right-handed
    float v01 = fmaf(v12,v20, -v22*v10);
    float v11 = fmaf(v22,v00, -v02*v20);
    float v21 = fmaf(v02,v10, -v12*v00);

    // ---- U columns: u_i = normalize(A v_i); sigma_i^2 = |A v_i|^2 ----
    float q0 = fmaf(a00,v00, fmaf(a01,v10, a02*v20));
    float q1 = fmaf(a10,v00, fmaf(a11,v10, a12*v20));
    float q2 = fmaf(a20,v00, fmaf(a21,v10, a22*v20));
    float m0 = fmaf(q0,q0, fmaf(q1,q1, q2*q2));
    float i0 = frsq(fmaxf(m0, 1e-30f));
    float u00 = q0*i0, u10 = q1*i0, u20 = q2*i0;

    q0 = fmaf(a00,v01, fmaf(a01,v11, a02*v21));
    q1 = fmaf(a10,v01, fmaf(a11,v11, a12*v21));
    q2 = fmaf(a20,v01, fmaf(a21,v11, a22*v21));
    float m1 = fmaf(q0,q0, fmaf(q1,q1, q2*q2));
    float i1 = frsq(fmaxf(m1, 1e-30f));
    float u01 = q0*i1, u11 = q1*i1, u21 = q2*i1;

    float u02 = fmaf(u10,u21, -u20*u11);       // u2 = u0 x u1
    float u12 = fmaf(u20,u01, -u00*u21);
    float u22 = fmaf(u00,u11, -u10*u01);

    // signed third singular term: s2 = u2^T A v2
    float w0 = fmaf(a00,v02, fmaf(a01,v12, a02*v22));
    float w1 = fmaf(a10,v02, fmaf(a11,v12, a12*v22));
    float w2 = fmaf(a20,v02, fmaf(a21,v12, a22*v22));
    float s2 = fmaf(u02,w0, fmaf(u12,w1, u22*w2));

    // ---- Drucker-Prager return mapping on log strains ----
    float e0 = 0.5f * __logf(fmaxf(m0, 0.0025f));
    float e1 = 0.5f * __logf(fmaxf(m1, 0.0025f));
    float e2 = __logf(fmaxf(fabsf(s2), 0.05f));
    float tr  = e0 + e1 + e2;
    float tr3 = tr * (1.0f / 3.0f);
    float h0 = e0 - tr3, h1 = e1 - tr3, h2 = e2 - tr3;
    float hn = fsqrt_r(fmaf(h0,h0, fmaf(h1,h1, h2*h2)));
    hn = fmaxf(hn, 1e-10f);
    float st = tr - coh * 3.0f;
    float dg = hn + ratio * st;
    float sc = fmaxf(dg, 0.0f) * frcp(hn);
    bool yield = st < 0.0f;
    float ec0 = yield ? fmaf(-sc, h0, e0) : coh;
    float ec1 = yield ? fmaf(-sc, h1, e1) : coh;
    float ec2 = yield ? fmaf(-sc, h2, e2) : coh;
    float f0 = __expf(ec0);
    float f1 = __expf(ec1);
    float f2 = copysignf(__expf(ec2), s2);

    // ---- F_corrected = sum_k f_k * u_k * v_k^T ----
    float w00 = u00*f0, w01 = u01*f1, w02 = u02*f2;
    float w10 = u10*f0, w11 = u11*f1, w12 = u12*f2;
    float w20 = u20*f0, w21 = u21*f1, w22 = u22*f2;
    r00 = fmaf(w00,v00, fmaf(w01,v01, w02*v02));
    r01 = fmaf(w00,v10, fmaf(w01,v11, w02*v12));
    r02 = fmaf(w00,v20, fmaf(w01,v21, w02*v22));
    r10 = fmaf(w10,v00, fmaf(w11,v01, w12*v02));
    r11 = fmaf(w10,v10, fmaf(w11,v11, w12*v12));
    r12 = fmaf(w10,v20, fmaf(w11,v21, w12*v22));
    r20 = fmaf(w20,v00, fmaf(w21,v01, w22*v02));
    r21 = fmaf(w20,v10, fmaf(w21,v11, w22*v12));
    r22 = fmaf(w20,v20, fmaf(w21,v21, w22*v22));
}

__global__ __launch_bounds__(BLOCK) void dp_kernel(
    const float* __restrict__ F,
    const float* __restrict__ p_yml,
    const float* __restrict__ p_nu,
    const float* __restrict__ p_fa,
    const float* __restrict__ p_coh,
    float* __restrict__ out,
    int n_elem)
{
    __shared__ float lds[FPB];                 // 18 KiB: 8 blocks/CU still fit
    const int t_id    = threadIdx.x;
    const int nfloats = n_elem * 9;            // <= 36e6, fits int
    const int base_f  = (int)blockIdx.x * FPB; // 32-bit addressing

    // ---- stage in: coalesced float4 (1152 tiles, 4.5/thread) ----
    #pragma unroll
    for (int j = 0; j < 5; ++j) {
        int idx = t_id + j * BLOCK;
        if (idx < F4PB) {
            int g4 = (base_f >> 2) + idx;
            int gf = g4 << 2;
            if (gf + 4 <= nfloats) {
                ((float4*)lds)[idx] = ((const float4*)F)[g4];
            } else {
                #pragma unroll
                for (int k = 0; k < 4; ++k)
                    if (gf + k < nfloats) lds[idx * 4 + k] = F[gf + k];
            }
        }
    }
    __syncthreads();

    // ---- material params (uniform) ----
    const float yml = p_yml[0];
    const float nu  = p_nu[0];
    const float fa  = p_fa[0];
    const float coh = p_coh[0];
    const float E     = __expf(yml);
    const float sphi  = __sinf(fa * 0.017453292519943295f);
    const float alpha = 1.632993161855452f * sphi * frcp(3.0f - sphi);
    const float mu    = E * 0.5f * frcp(1.0f + nu);
    const float la    = E * nu * frcp((1.0f + nu) * (1.0f - 2.0f * nu));
    const float ratio = (3.0f * la + 2.0f * mu) * frcp(2.0f * mu) * alpha;

    // ---- load both owned records (thread t owns records t and t+BLOCK;
    //      stride-9 reads keep the free 2-way bank alias) ----
    const float* pA = lds + t_id * 9;
    const float* pB = lds + (t_id + BLOCK) * 9;
    float A00=pA[0], A01=pA[1], A02=pA[2];
    float A10=pA[3], A11=pA[4], A12=pA[5];
    float A20=pA[6], A21=pA[7], A22=pA[8];
    float B00=pB[0], B01=pB[1], B02=pB[2];
    float B10=pB[3], B11=pB[4], B12=pB[5];
    float B20=pB[6], B21=pB[7], B22=pB[8];

    // ---- two independent solves: scheduler interleaves the chains ----
    float xa0,xa1,xa2,xa3,xa4,xa5,xa6,xa7,xa8;
    float xb0,xb1,xb2,xb3,xb4,xb5,xb6,xb7,xb8;
    dp_solve(A00,A01,A02,A10,A11,A12,A20,A21,A22, coh, ratio,
             xa0,xa1,xa2,xa3,xa4,xa5,xa6,xa7,xa8);
    dp_solve(B00,B01,B02,B10,B11,B12,B20,B21,B22, coh, ratio,
             xb0,xb1,xb2,xb3,xb4,xb5,xb6,xb7,xb8);

    // ---- write results to own records (same-thread slots: no barrier
    //      needed between read and write; cross-thread copy-out below) ----
    {
        float* q = lds + t_id * 9;
        q[0]=xa0; q[1]=xa1; q[2]=xa2;
        q[3]=xa3; q[4]=xa4; q[5]=xa5;
        q[6]=xa6; q[7]=xa7; q[8]=xa8;
        q = lds + (t_id + BLOCK) * 9;
        q[0]=xb0; q[1]=xb1; q[2]=xb2;
        q[3]=xb3; q[4]=xb4; q[5]=xb5;
        q[6]=xb6; q[7]=xb7; q[8]=xb8;
    }
    __syncthreads();

    // ---- stage out: coalesced float4 ----
    #pragma unroll
    for (int j = 0; j < 5; ++j) {
        int idx = t_id + j * BLOCK;
        if (idx < F4PB) {
            int g4 = (base_f >> 2) + idx;
            int gf = g4 << 2;
            if (gf + 4 <= nfloats) {
                ((float4*)out)[g4] = ((float4*)lds)[idx];
            } else {
                #pragma unroll
                for (int k = 0; k < 4; ++k)
                    if (gf + k < nfloats) out[gf + k] = lds[idx * 4 + k];
            }
        }
    }
}

extern "C" void kernel_launch(void* const* d_in, const int* in_sizes, int n_in,
                              void* d_out, int out_size, void* d_ws, size_t ws_size,
                              hipStream_t stream) {
    const float* F = (const float*)d_in[0];
    const int n_elem = in_sizes[0] / 9;
    const int grid = (n_elem + EPB - 1) / EPB;
    dp_kernel<<<grid, BLOCK, 0, stream>>>(
        F,
        (const float*)d_in[1], (const float*)d_in[2],
        (const float*)d_in[3], (const float*)d_in[4],
        (float*)d_out, n_elem);
}

// Round 4
// 255.594 us; speedup vs baseline: 1.0098x; 1.0064x over previous
//
#include <hip/hip_runtime.h>
#include <math.h>

#define BLOCK 256

__device__ __forceinline__ float frcp(float x)   { return __builtin_amdgcn_rcpf(x); }
__device__ __forceinline__ float frsq(float x)   { return __builtin_amdgcn_rsqf(x); }
__device__ __forceinline__ float fsqrt_r(float x){ return __builtin_amdgcn_sqrtf(x); }

// Hastings acos approximation, abs err ~6.8e-5 rad (feeds only eigenvector
// extraction; sigma is recovered variationally so this precision is ample).
__device__ __forceinline__ float acos_fast(float x) {
    float ax = fabsf(x);
    float p = fmaf(ax, -0.0187293f, 0.0742610f);
    p = fmaf(ax, p, -0.2121144f);
    p = fmaf(ax, p, 1.5707288f);
    float r = fsqrt_r(fmaxf(1.0f - ax, 0.0f)) * p;
    return (x < 0.0f) ? (3.14159265358979f - r) : r;
}

// Largest-norm cross product among the three row pairs of a symmetric 3x3.
__device__ __forceinline__ void best_cross(
    float r0x, float r0y, float r0z,
    float r1x, float r1y, float r1z,
    float r2x, float r2y, float r2z,
    float& bx, float& by, float& bz, float& bn)
{
    float c0x = fmaf(r0y,r1z, -r0z*r1y);   // row0 x row1
    float c0y = fmaf(r0z,r1x, -r0x*r1z);
    float c0z = fmaf(r0x,r1y, -r0y*r1x);
    float c1x = fmaf(r0y,r2z, -r0z*r2y);   // row0 x row2
    float c1y = fmaf(r0z,r2x, -r0x*r2z);
    float c1z = fmaf(r0x,r2y, -r0y*r2x);
    float c2x = fmaf(r1y,r2z, -r1z*r2y);   // row1 x row2
    float c2y = fmaf(r1z,r2x, -r1x*r2z);
    float c2z = fmaf(r1x,r2y, -r1y*r2x);
    float n0 = fmaf(c0x,c0x, fmaf(c0y,c0y, c0z*c0z));
    float n1 = fmaf(c1x,c1x, fmaf(c1y,c1y, c1z*c1z));
    float n2 = fmaf(c2x,c2x, fmaf(c2y,c2y, c2z*c2z));
    bool b1 = n1 > n0;
    float sx = b1 ? c1x : c0x, sy = b1 ? c1y : c0y, sz = b1 ? c1z : c0z;
    float sn = b1 ? n1 : n0;
    bool b2 = n2 > sn;
    bx = b2 ? c2x : sx; by = b2 ? c2y : sy; bz = b2 ? c2z : sz;
    bn = b2 ? n2 : sn;
}

// Closed-form 3x3 SVD (symmetric eigensolve of A^T A) + Drucker-Prager
// return mapping. Identical expression tree to R2/R3 (absmax canary).
__device__ __forceinline__ void dp_solve(
    float a00, float a01, float a02,
    float a10, float a11, float a12,
    float a20, float a21, float a22,
    float coh, float ratio,
    float& r00, float& r01, float& r02,
    float& r10, float& r11, float& r12,
    float& r20, float& r21, float& r22)
{
    // ---- Gram matrix S = A^T A ----
    float s00 = fmaf(a00,a00, fmaf(a10,a10, a20*a20));
    float s11 = fmaf(a01,a01, fmaf(a11,a11, a21*a21));
    float s22 = fmaf(a02,a02, fmaf(a12,a12, a22*a22));
    float s01 = fmaf(a00,a01, fmaf(a10,a11, a20*a21));
    float s02 = fmaf(a00,a02, fmaf(a10,a12, a20*a22));
    float s12 = fmaf(a01,a02, fmaf(a11,a12, a21*a22));

    // ---- closed-form eigenvalues (trigonometric cubic) ----
    float q   = (s00 + s11 + s22) * (1.0f/3.0f);
    float b00 = s00 - q, b11 = s11 - q, b22 = s22 - q;
    float offsq = fmaf(s01,s01, fmaf(s02,s02, s12*s12));
    float p2  = fmaf(b00,b00, fmaf(b11,b11, fmaf(b22,b22, 2.0f*offsq)));
    float pp  = fsqrt_r(p2 * (1.0f/6.0f));
    float pinv = frcp(fmaxf(pp, 1e-10f));       // clamp: pinv^3 <= 1e30, no Inf
    float det = b00*fmaf(b11,b22, -s12*s12)
              - s01*fmaf(s01,b22, -s12*s02)
              + s02*fmaf(s01,s12, -b11*s02);
    float rdet = 0.5f * det * pinv * pinv * pinv;
    rdet = fminf(fmaxf(rdet, -1.0f), 1.0f);
    float phi  = acos_fast(rdet) * (1.0f/3.0f);          // in [0, pi/3]
    float lam0 = fmaf(2.0f*pp, __cosf(phi), q);                       // largest
    float lam2 = fmaf(2.0f*pp, __cosf(phi + 2.0943951023931953f), q); // smallest

    // ---- v0: null direction of (S - lam0 I) ----
    float bx, by, bz, bn;
    best_cross(s00-lam0, s01, s02,
               s01, s11-lam0, s12,
               s02, s12, s22-lam0, bx, by, bz, bn);
    bool ok0 = bn > 1e-24f;
    float ir0 = frsq(fmaxf(bn, 1e-30f));
    float v00 = ok0 ? bx*ir0 : 1.0f;
    float v10 = ok0 ? by*ir0 : 0.0f;
    float v20 = ok0 ? bz*ir0 : 0.0f;

    // ---- v2: null direction of (S - lam2 I), orthogonalized against v0 ----
    best_cross(s00-lam2, s01, s02,
               s01, s11-lam2, s12,
               s02, s12, s22-lam2, bx, by, bz, bn);
    float axv = fabsf(v00), ayv = fabsf(v10), azv = fabsf(v20);
    bool xm = (axv <= ayv) && (axv <= azv);
    bool ym = (!xm) && (ayv <= azv);
    float ex = xm ? 1.0f : 0.0f;
    float ey = ym ? 1.0f : 0.0f;
    float ez = (xm || ym) ? 0.0f : 1.0f;
    float fx = fmaf(v10,ez, -v20*ey);          // fallback perp to v0
    float fy = fmaf(v20,ex, -v00*ez);
    float fz = fmaf(v00,ey, -v10*ex);
    bool ok2 = bn > 1e-24f;
    float wx = ok2 ? bx : fx, wy = ok2 ? by : fy, wz = ok2 ? bz : fz;
    float dp = fmaf(wx,v00, fmaf(wy,v10, wz*v20));   // Gram-Schmidt vs v0
    wx = fmaf(-dp, v00, wx); wy = fmaf(-dp, v10, wy); wz = fmaf(-dp, v20, wz);
    float wn = fmaf(wx,wx, fmaf(wy,wy, wz*wz));
    bool okw = wn > 1e-24f;
    wx = okw ? wx : fx; wy = okw ? wy : fy; wz = okw ? wz : fz;
    wn = okw ? wn : fmaf(fx,fx, fmaf(fy,fy, fz*fz));
    float irw = frsq(fmaxf(wn, 1e-30f));
    float v02 = wx*irw, v12 = wy*irw, v22 = wz*irw;
    // v1 = v2 x v0 -> (v0,v1,v2) right-handed
    float v01 = fmaf(v12,v20, -v22*v10);
    float v11 = fmaf(v22,v00, -v02*v20);
    float v21 = fmaf(v02,v10, -v12*v00);

    // ---- U columns: u_i = normalize(A v_i); sigma_i^2 = |A v_i|^2 ----
    float q0 = fmaf(a00,v00, fmaf(a01,v10, a02*v20));
    float q1 = fmaf(a10,v00, fmaf(a11,v10, a12*v20));
    float q2 = fmaf(a20,v00, fmaf(a21,v10, a22*v20));
    float m0 = fmaf(q0,q0, fmaf(q1,q1, q2*q2));
    float i0 = frsq(fmaxf(m0, 1e-30f));
    float u00 = q0*i0, u10 = q1*i0, u20 = q2*i0;

    q0 = fmaf(a00,v01, fmaf(a01,v11, a02*v21));
    q1 = fmaf(a10,v01, fmaf(a11,v11, a12*v21));
    q2 = fmaf(a20,v01, fmaf(a21,v11, a22*v21));
    float m1 = fmaf(q0,q0, fmaf(q1,q1, q2*q2));
    float i1 = frsq(fmaxf(m1, 1e-30f));
    float u01 = q0*i1, u11 = q1*i1, u21 = q2*i1;

    float u02 = fmaf(u10,u21, -u20*u11);       // u2 = u0 x u1
    float u12 = fmaf(u20,u01, -u00*u21);
    float u22 = fmaf(u00,u11, -u10*u01);

    // signed third singular term: s2 = u2^T A v2
    float w0 = fmaf(a00,v02, fmaf(a01,v12, a02*v22));
    float w1 = fmaf(a10,v02, fmaf(a11,v12, a12*v22));
    float w2 = fmaf(a20,v02, fmaf(a21,v12, a22*v22));
    float s2 = fmaf(u02,w0, fmaf(u12,w1, u22*w2));

    // ---- Drucker-Prager return mapping on log strains ----
    float e0 = 0.5f * __logf(fmaxf(m0, 0.0025f));
    float e1 = 0.5f * __logf(fmaxf(m1, 0.0025f));
    float e2 = __logf(fmaxf(fabsf(s2), 0.05f));
    float tr  = e0 + e1 + e2;
    float tr3 = tr * (1.0f / 3.0f);
    float h0 = e0 - tr3, h1 = e1 - tr3, h2 = e2 - tr3;
    float hn = fsqrt_r(fmaf(h0,h0, fmaf(h1,h1, h2*h2)));
    hn = fmaxf(hn, 1e-10f);
    float st = tr - coh * 3.0f;
    float dg = hn + ratio * st;
    float sc = fmaxf(dg, 0.0f) * frcp(hn);
    bool yield = st < 0.0f;
    float ec0 = yield ? fmaf(-sc, h0, e0) : coh;
    float ec1 = yield ? fmaf(-sc, h1, e1) : coh;
    float ec2 = yield ? fmaf(-sc, h2, e2) : coh;
    float f0 = __expf(ec0);
    float f1 = __expf(ec1);
    float f2 = copysignf(__expf(ec2), s2);

    // ---- F_corrected = sum_k f_k * u_k * v_k^T ----
    float w00 = u00*f0, w01 = u01*f1, w02 = u02*f2;
    float w10 = u10*f0, w11 = u11*f1, w12 = u12*f2;
    float w20 = u20*f0, w21 = u21*f1, w22 = u22*f2;
    r00 = fmaf(w00,v00, fmaf(w01,v01, w02*v02));
    r01 = fmaf(w00,v10, fmaf(w01,v11, w02*v12));
    r02 = fmaf(w00,v20, fmaf(w01,v21, w02*v22));
    r10 = fmaf(w10,v00, fmaf(w11,v01, w12*v02));
    r11 = fmaf(w10,v10, fmaf(w11,v11, w12*v12));
    r12 = fmaf(w10,v20, fmaf(w11,v21, w12*v22));
    r20 = fmaf(w20,v00, fmaf(w21,v01, w22*v02));
    r21 = fmaf(w20,v10, fmaf(w21,v11, w22*v12));
    r22 = fmaf(w20,v20, fmaf(w21,v21, w22*v22));
}

// Pure map kernel: no LDS, no barriers, no inter-thread coupling.
// A wave's 9 adjacent dword loads cover one contiguous 2304 B span;
// SILoadStoreOptimizer merges to dwordx4+dwordx4+dword (global multi-dword
// needs only dword alignment on gfx9+), and L1 absorbs the line-granular
// overlap. __launch_bounds__(256,8): pin <=64 VGPR -> 8 waves/SIMD.
__global__ __launch_bounds__(BLOCK, 8) void dp_kernel(
    const float* __restrict__ F,
    const float* __restrict__ p_yml,
    const float* __restrict__ p_nu,
    const float* __restrict__ p_fa,
    const float* __restrict__ p_coh,
    float* __restrict__ out,
    int n_elem)
{
    const int e = (int)blockIdx.x * BLOCK + threadIdx.x;
    if (e >= n_elem) return;

    // ---- direct load of own record (36 B, dword-aligned) ----
    const float* p = F + e * 9;
    float a00 = p[0], a01 = p[1], a02 = p[2];
    float a10 = p[3], a11 = p[4], a12 = p[5];
    float a20 = p[6], a21 = p[7], a22 = p[8];

    // ---- material params (uniform) ----
    const float yml = p_yml[0];
    const float nu  = p_nu[0];
    const float fa  = p_fa[0];
    const float coh = p_coh[0];
    const float E     = __expf(yml);
    const float sphi  = __sinf(fa * 0.017453292519943295f);
    const float alpha = 1.632993161855452f * sphi * frcp(3.0f - sphi);
    const float mu    = E * 0.5f * frcp(1.0f + nu);
    const float la    = E * nu * frcp((1.0f + nu) * (1.0f - 2.0f * nu));
    const float ratio = (3.0f * la + 2.0f * mu) * frcp(2.0f * mu) * alpha;

    float r00,r01,r02,r10,r11,r12,r20,r21,r22;
    dp_solve(a00,a01,a02,a10,a11,a12,a20,a21,a22, coh, ratio,
             r00,r01,r02,r10,r11,r12,r20,r21,r22);

    // ---- direct store of own record ----
    float* o = out + e * 9;
    o[0]=r00; o[1]=r01; o[2]=r02;
    o[3]=r10; o[4]=r11; o[5]=r12;
    o[6]=r20; o[7]=r21; o[8]=r22;
}

extern "C" void kernel_launch(void* const* d_in, const int* in_sizes, int n_in,
                              void* d_out, int out_size, void* d_ws, size_t ws_size,
                              hipStream_t stream) {
    const float* F = (const float*)d_in[0];
    const int n_elem = in_sizes[0] / 9;
    const int grid = (n_elem + BLOCK - 1) / BLOCK;
    dp_kernel<<<grid, BLOCK, 0, stream>>>(
        F,
        (const float*)d_in[1], (const float*)d_in[2],
        (const float*)d_in[3], (const float*)d_in[4],
        (float*)d_out, n_elem);
}